// Round 2
// baseline (349.001 us; speedup 1.0000x reference)
//
#include <hip/hip_runtime.h>

#define M_ROWS 12608          // 64*197
#define K_DIM  768
#define N3     2304
#define QSZ    9682944        // 64*12*197*64 elements per q/k/v plane
#define WT_OFF (3*QSZ)        // Wt offset in ws (ushort elements)

typedef __bf16 bf16x8 __attribute__((ext_vector_type(8)));
typedef float  f32x4  __attribute__((ext_vector_type(4)));

__device__ __forceinline__ unsigned short f2bf(float f) {
    unsigned u = __builtin_bit_cast(unsigned, f);
    u += 0x7fffu + ((u >> 16) & 1u);          // RNE, inputs are finite
    return (unsigned short)(u >> 16);
}

// ---------------- Kernel 1: W [768,2304] fp32 -> Wt [2304,768] bf16 ----------------
__global__ void wtrans_kernel(const float* __restrict__ W, unsigned short* __restrict__ Wt) {
    __shared__ float tile[32][33];
    int n0 = blockIdx.x * 32, k0 = blockIdx.y * 32;
    int tx = threadIdx.x, ty = threadIdx.y;
#pragma unroll
    for (int i = 0; i < 4; ++i)
        tile[ty + i * 8][tx] = W[(size_t)(k0 + ty + i * 8) * N3 + n0 + tx];
    __syncthreads();
#pragma unroll
    for (int i = 0; i < 4; ++i)
        Wt[(size_t)(n0 + ty + i * 8) * K_DIM + k0 + tx] = f2bf(tile[tx][ty + i * 8]);
}

// ---------------- Kernel 2: QKV GEMM (bf16 MFMA) + bias + scale + scatter ----------------
// C[m][n] = X[m][:] . W[:][n]; output scattered to q/k/v [B,H,N,d] bf16 planes in ws.
__global__ __launch_bounds__(256, 2) void qkv_gemm_kernel(
        const float* __restrict__ X, const unsigned short* __restrict__ Wt,
        const float* __restrict__ bias, unsigned short* __restrict__ qkv) {
    __shared__ __align__(16) unsigned short As[128 * 40];   // [row][k] stride 40 (pad)
    __shared__ __align__(16) unsigned short Bs[128 * 40];   // [n][k]   stride 40 (pad)

    const int m0 = blockIdx.y * 128, n0 = blockIdx.x * 128;
    const int t = threadIdx.x;
    const int w = t >> 6, lane = t & 63, quad = lane >> 4, l16 = lane & 15;
    const int wr = (w >> 1) * 64, wc = (w & 1) * 64;

    f32x4 acc[4][4];
#pragma unroll
    for (int i = 0; i < 4; ++i)
#pragma unroll
        for (int j = 0; j < 4; ++j) acc[i][j] = (f32x4){0.f, 0.f, 0.f, 0.f};

    for (int k0 = 0; k0 < K_DIM; k0 += 32) {
        // stage A: 128 rows x 32 fp32 -> bf16 LDS  (1024 float4 / 256 thr)
#pragma unroll
        for (int i = 0; i < 4; ++i) {
            int f = t + 256 * i;
            int row = f >> 3, c4 = (f & 7) * 4;
            int gm = m0 + row;
            float4 v = make_float4(0.f, 0.f, 0.f, 0.f);
            if (gm < M_ROWS) v = *(const float4*)(X + (size_t)gm * K_DIM + k0 + c4);
            ushort4 hv;
            hv.x = f2bf(v.x); hv.y = f2bf(v.y); hv.z = f2bf(v.z); hv.w = f2bf(v.w);
            *(ushort4*)&As[row * 40 + c4] = hv;
        }
        // stage B: 128 n-rows x 32 bf16 from Wt (512 uint4 / 256 thr)
#pragma unroll
        for (int i = 0; i < 2; ++i) {
            int f = t + 256 * i;
            int row = f >> 2, c8 = (f & 3) * 8;
            *(uint4*)&Bs[row * 40 + c8] =
                *(const uint4*)(Wt + (size_t)(n0 + row) * K_DIM + k0 + c8);
        }
        __syncthreads();
        // one 16x16x32 MFMA consumes the whole BK=32 tile (k = quad*8 + j)
        {
            bf16x8 af[4], bfr[4];
#pragma unroll
            for (int i = 0; i < 4; ++i)
                af[i] = *(const bf16x8*)&As[(wr + i * 16 + l16) * 40 + quad * 8];
#pragma unroll
            for (int j = 0; j < 4; ++j)
                bfr[j] = *(const bf16x8*)&Bs[(wc + j * 16 + l16) * 40 + quad * 8];
#pragma unroll
            for (int i = 0; i < 4; ++i)
#pragma unroll
                for (int j = 0; j < 4; ++j)
                    acc[i][j] = __builtin_amdgcn_mfma_f32_16x16x32_bf16(af[i], bfr[j], acc[i][j], 0, 0, 0);
        }
        __syncthreads();
    }

    // epilogue: bias, fold 1/sqrt(64) into q, scatter to [B,H,N,d] bf16
#pragma unroll
    for (int i = 0; i < 4; ++i) {
#pragma unroll
        for (int j = 0; j < 4; ++j) {
            int gn = n0 + wc + j * 16 + l16;
            int which = gn / 768;
            int rem = gn - which * 768;
            int hh = rem >> 6, dd = rem & 63;
            float bv = bias[gn];
#pragma unroll
            for (int r = 0; r < 4; ++r) {
                int gm = m0 + wr + i * 16 + quad * 4 + r;
                if (gm >= M_ROWS) continue;
                int bb = gm / 197;
                int tok = gm - bb * 197;
                float val = acc[i][j][r] + bv;
                if (which == 0) val *= 0.125f;
                size_t dst = (size_t)which * QSZ +
                             ((size_t)((bb * 12 + hh) * 197 + tok) * 64 + dd);
                qkv[dst] = f2bf(val);
            }
        }
    }
}

// ---------------- Kernel 3: fused attention per (qtile, head, batch) ----------------
__global__ __launch_bounds__(256, 2) void attn_kernel(
        const unsigned short* __restrict__ qkv, float* __restrict__ out) {
    __shared__ __align__(16) unsigned short Ks[208 * 72];     // [kt][d]  stride 72
    __shared__ __align__(16) unsigned short Vt[64 * 232];     // [d][kt]  stride 232
    __shared__ __align__(16) unsigned short Ps[4 * 16 * 232]; // per-wave P, stride 232

    const int qt = blockIdx.x, h = blockIdx.y, b = blockIdx.z;
    const int t = threadIdx.x, w = t >> 6, lane = t & 63;
    const int quad = lane >> 4, l16 = lane & 15;

    const size_t headoff = (size_t)((b * 12 + h) * 197) * 64;
    const unsigned short* Qg = qkv + headoff;
    const unsigned short* Kg = qkv + (size_t)QSZ + headoff;
    const unsigned short* Vg = qkv + (size_t)2 * QSZ + headoff;

    // zero P buffers (covers padded cols so 0*0=0 in PV, never NaN)
    uint4 z4; z4.x = z4.y = z4.z = z4.w = 0u;
    for (int i = t; i < (4 * 16 * 232) / 8; i += 256) ((uint4*)Ps)[i] = z4;

    // stage K: 197 x 64 bf16, 16B chunks; zero rows 197..207 (masked later anyway)
    for (int idx = t; idx < 208 * 8; idx += 256) {
        int row = idx >> 3, c8 = (idx & 7) * 8;
        uint4 kv = z4;
        if (row < 197) kv = *(const uint4*)(Kg + (size_t)row * 64 + c8);
        *(uint4*)&Ks[row * 72 + c8] = kv;
    }
    // stage V transposed, zero-padded to kt=231
    for (int idx = t; idx < 58 * 64; idx += 256) {
        int g = idx >> 6, dd = idx & 63;
        int kt = g * 4;
        ushort4 vv;
        vv.x = (kt + 0 < 197) ? Vg[(size_t)(kt + 0) * 64 + dd] : (unsigned short)0;
        vv.y = (kt + 1 < 197) ? Vg[(size_t)(kt + 1) * 64 + dd] : (unsigned short)0;
        vv.z = (kt + 2 < 197) ? Vg[(size_t)(kt + 2) * 64 + dd] : (unsigned short)0;
        vv.w = (kt + 3 < 197) ? Vg[(size_t)(kt + 3) * 64 + dd] : (unsigned short)0;
        *(ushort4*)&Vt[dd * 232 + kt] = vv;
    }
    __syncthreads();

    // Q fragments straight from global (A-layout: m=l16, k=quad*8+j)
    int qrow = qt * 64 + w * 16 + l16;
    int tokq = qrow < 197 ? qrow : 196;
    bf16x8 aq0 = *(const bf16x8*)(Qg + (size_t)tokq * 64 + quad * 8);
    bf16x8 aq1 = *(const bf16x8*)(Qg + (size_t)tokq * 64 + 32 + quad * 8);

    // scores: S[16 q-rows][208 kt-cols], 13 chunks of 16 cols
    f32x4 s[13];
#pragma unroll
    for (int c = 0; c < 13; ++c) {
        bf16x8 b0 = *(const bf16x8*)&Ks[(c * 16 + l16) * 72 + quad * 8];
        bf16x8 b1 = *(const bf16x8*)&Ks[(c * 16 + l16) * 72 + 32 + quad * 8];
        f32x4 zz = (f32x4){0.f, 0.f, 0.f, 0.f};
        zz = __builtin_amdgcn_mfma_f32_16x16x32_bf16(aq0, b0, zz, 0, 0, 0);
        zz = __builtin_amdgcn_mfma_f32_16x16x32_bf16(aq1, b1, zz, 0, 0, 0);
        s[c] = zz;
    }
    // mask cols >= 197 (only chunk 12: cols 192+l16)
    if (l16 >= 5) { s[12][0] = -1e30f; s[12][1] = -1e30f; s[12][2] = -1e30f; s[12][3] = -1e30f; }

    // softmax: row max + exp + row sum. D-layout row = quad*4 + r; cols spread over l16.
    float mx[4], lsum[4];
#pragma unroll
    for (int r = 0; r < 4; ++r) {
        float m = s[0][r];
#pragma unroll
        for (int c = 1; c < 13; ++c) m = fmaxf(m, s[c][r]);
#pragma unroll
        for (int d = 1; d < 16; d <<= 1) m = fmaxf(m, __shfl_xor(m, d));
        mx[r] = m;
        lsum[r] = 0.f;
    }
#pragma unroll
    for (int c = 0; c < 13; ++c)
#pragma unroll
        for (int r = 0; r < 4; ++r) {
            float p = __expf(s[c][r] - mx[r]);
            s[c][r] = p;
            lsum[r] += p;
        }
#pragma unroll
    for (int r = 0; r < 4; ++r)
#pragma unroll
        for (int d = 1; d < 16; d <<= 1) lsum[r] += __shfl_xor(lsum[r], d);

    // P -> per-wave LDS (D-layout -> A-layout round trip)
    unsigned short* Pw = Ps + w * (16 * 232);
#pragma unroll
    for (int c = 0; c < 13; ++c)
#pragma unroll
        for (int r = 0; r < 4; ++r)
            Pw[(quad * 4 + r) * 232 + c * 16 + l16] = f2bf(s[c][r]);

    // PV: ctx[16][64], K-dim = 224 (zero padded beyond 207; cols 197..207 p==0)
    f32x4 o[4];
#pragma unroll
    for (int j = 0; j < 4; ++j) o[j] = (f32x4){0.f, 0.f, 0.f, 0.f};
#pragma unroll
    for (int kc = 0; kc < 7; ++kc) {
        int kof = kc * 32 + quad * 8;
        bf16x8 ap = *(const bf16x8*)&Pw[l16 * 232 + kof];
#pragma unroll
        for (int j = 0; j < 4; ++j) {
            bf16x8 bv = *(const bf16x8*)&Vt[(j * 16 + l16) * 232 + kof];
            o[j] = __builtin_amdgcn_mfma_f32_16x16x32_bf16(ap, bv, o[j], 0, 0, 0);
        }
    }

    // epilogue: divide by l, store fp32 [B, tok, 768]
    int tokbase = qt * 64 + w * 16 + quad * 4;
#pragma unroll
    for (int r = 0; r < 4; ++r) {
        int tr = tokbase + r;
        if (tr >= 197) continue;
        float inv = 1.f / lsum[r];
#pragma unroll
        for (int j = 0; j < 4; ++j)
            out[((size_t)(b * 197 + tr)) * 768 + h * 64 + j * 16 + l16] = o[j][r] * inv;
    }
}

extern "C" void kernel_launch(void* const* d_in, const int* in_sizes, int n_in,
                              void* d_out, int out_size, void* d_ws, size_t ws_size,
                              hipStream_t stream) {
    const float* X    = (const float*)d_in[0];   // [64,197,768]
    const float* W    = (const float*)d_in[1];   // [768,2304]
    const float* bias = (const float*)d_in[2];   // [2304]
    unsigned short* ws = (unsigned short*)d_ws;  // q|k|v bf16 planes then Wt bf16
    float* out = (float*)d_out;                  // [64,197,768]

    wtrans_kernel<<<dim3(72, 24), dim3(32, 8), 0, stream>>>(W, ws + WT_OFF);
    qkv_gemm_kernel<<<dim3(18, 99), 256, 0, stream>>>(X, ws + WT_OFF, bias, ws);
    attn_kernel<<<dim3(4, 12, 64), 256, 0, stream>>>(ws, out);
}

// Round 3
// 235.167 us; speedup vs baseline: 1.4841x; 1.4841x over previous
//
#include <hip/hip_runtime.h>

#define M_ROWS 12608          // 64*197
#define K_DIM  768
#define QSZ    9682944        // 64*12*197*64 elements per q/k/v plane
#define WT_OFF (3*QSZ)        // Wt offset in ws (ushort elements)

typedef __bf16 bf16x8 __attribute__((ext_vector_type(8)));
typedef float  f32x4  __attribute__((ext_vector_type(4)));

__device__ __forceinline__ unsigned short f2bf(float f) {
    unsigned u = __builtin_bit_cast(unsigned, f);
    u += 0x7fffu + ((u >> 16) & 1u);          // RNE, inputs are finite
    return (unsigned short)(u >> 16);
}

__device__ __forceinline__ void gll16(const unsigned short* g, unsigned short* l) {
    __builtin_amdgcn_global_load_lds(
        (const __attribute__((address_space(1))) unsigned int*)g,
        (__attribute__((address_space(3))) unsigned int*)l, 16, 0, 0);
}

// ---------------- Kernel 0: X fp32 -> bf16 (stored in d_out scratch area) ----------------
__global__ void x2bf_kernel(const float* __restrict__ X, unsigned short* __restrict__ Xb) {
    size_t base = ((size_t)blockIdx.x * 256 + threadIdx.x) * 8;
    float4 a = *(const float4*)(X + base);
    float4 b = *(const float4*)(X + base + 4);
    ushort4 lo, hi;
    lo.x = f2bf(a.x); lo.y = f2bf(a.y); lo.z = f2bf(a.z); lo.w = f2bf(a.w);
    hi.x = f2bf(b.x); hi.y = f2bf(b.y); hi.z = f2bf(b.z); hi.w = f2bf(b.w);
    *(ushort4*)(Xb + base) = lo;
    *(ushort4*)(Xb + base + 4) = hi;
}

// ---------------- Kernel 1: W [768,2304] fp32 -> Wt [2304,768] bf16 ----------------
__global__ void wtrans_kernel(const float* __restrict__ W, unsigned short* __restrict__ Wt) {
    __shared__ float tile[32][33];
    int n0 = blockIdx.x * 32, k0 = blockIdx.y * 32;
    int tx = threadIdx.x, ty = threadIdx.y;
#pragma unroll
    for (int i = 0; i < 4; ++i)
        tile[ty + i * 8][tx] = W[(size_t)(k0 + ty + i * 8) * 2304 + n0 + tx];
    __syncthreads();
#pragma unroll
    for (int i = 0; i < 4; ++i)
        Wt[(size_t)(n0 + ty + i * 8) * K_DIM + k0 + tx] = f2bf(tile[tx][ty + i * 8]);
}

// ---------------- Kernel 2: QKV GEMM, global_load_lds staging, k-major LDS ----------------
// LDS layout: chunk s (16B) at offset s*16B; s = kchunk*128 + row  (kchunk=k/8, 4 per BK=32)
__global__ __launch_bounds__(256, 2) void qkv_gemm_kernel(
        const unsigned short* __restrict__ Xb, const unsigned short* __restrict__ Wt,
        const float* __restrict__ bias, unsigned short* __restrict__ qkv) {
    __shared__ __align__(16) unsigned short As[4096];   // 8 KB
    __shared__ __align__(16) unsigned short Bs[4096];   // 8 KB

    const int m0 = blockIdx.y * 128, n0 = blockIdx.x * 128;
    const int t = threadIdx.x;
    const int w = t >> 6, lane = t & 63, quad = lane >> 4, l16 = lane & 15;
    const int wr = (w >> 1) * 64, wc = (w & 1) * 64;

    // per-lane staging source (row, kchunk) for the two instrs this wave issues
    const int s0 = w * 128 + lane;            // i=0 chunk idx
    const int r0 = s0 & 127, kc0 = s0 >> 7;
    const int s1 = s0 + 64;                   // i=1 chunk idx
    const int r1 = s1 & 127, kc1 = s1 >> 7;
    const unsigned short* a0 = Xb + (size_t)(m0 + r0) * K_DIM + kc0 * 8;
    const unsigned short* a1 = Xb + (size_t)(m0 + r1) * K_DIM + kc1 * 8;
    const unsigned short* b0 = Wt + (size_t)(n0 + r0) * K_DIM + kc0 * 8;
    const unsigned short* b1 = Wt + (size_t)(n0 + r1) * K_DIM + kc1 * 8;

    f32x4 acc[4][4];
#pragma unroll
    for (int i = 0; i < 4; ++i)
#pragma unroll
        for (int j = 0; j < 4; ++j) acc[i][j] = (f32x4){0.f, 0.f, 0.f, 0.f};

    for (int k0 = 0; k0 < K_DIM; k0 += 32) {
        gll16(a0 + k0, &As[(w * 128) * 8]);
        gll16(a1 + k0, &As[(w * 128 + 64) * 8]);
        gll16(b0 + k0, &Bs[(w * 128) * 8]);
        gll16(b1 + k0, &Bs[(w * 128 + 64) * 8]);
        __syncthreads();
        bf16x8 af[4], bfr[4];
#pragma unroll
        for (int i = 0; i < 4; ++i)
            af[i] = *(const bf16x8*)&As[quad * 1024 + (wr + i * 16 + l16) * 8];
#pragma unroll
        for (int j = 0; j < 4; ++j)
            bfr[j] = *(const bf16x8*)&Bs[quad * 1024 + (wc + j * 16 + l16) * 8];
#pragma unroll
        for (int i = 0; i < 4; ++i)
#pragma unroll
            for (int j = 0; j < 4; ++j)
                acc[i][j] = __builtin_amdgcn_mfma_f32_16x16x32_bf16(af[i], bfr[j], acc[i][j], 0, 0, 0);
        __syncthreads();
    }

    // epilogue: bias, fold 1/sqrt(64) into q, scatter to [B,H,N,d] bf16
#pragma unroll
    for (int i = 0; i < 4; ++i) {
#pragma unroll
        for (int j = 0; j < 4; ++j) {
            int gn = n0 + wc + j * 16 + l16;
            int which = gn / 768;
            int rem = gn - which * 768;
            int hh = rem >> 6, dd = rem & 63;
            float bv = bias[gn];
#pragma unroll
            for (int r = 0; r < 4; ++r) {
                int gm = m0 + wr + i * 16 + quad * 4 + r;
                if (gm >= M_ROWS) continue;
                int bb = gm / 197;
                int tok = gm - bb * 197;
                float val = acc[i][j][r] + bv;
                if (which == 0) val *= 0.125f;
                size_t dst = (size_t)which * QSZ +
                             ((size_t)((bb * 12 + hh) * 197 + tok) * 64 + dd);
                qkv[dst] = f2bf(val);
            }
        }
    }
}

// ---------------- Kernel 3: fused attention, one block per (b,h) ----------------
__global__ __launch_bounds__(256, 2) void attn_kernel(
        const unsigned short* __restrict__ qkv, float* __restrict__ out) {
    __shared__ __align__(16) unsigned short Ks[197 * 72];     // 28368 B
    __shared__ __align__(16) unsigned short Vt[64 * 232];     // 29696 B
    __shared__ __align__(16) unsigned short Ps[4 * 16 * 136]; // 17408 B  (per-wave 16x136)

    const int h = blockIdx.x, b = blockIdx.y;
    const int t = threadIdx.x, w = t >> 6, lane = t & 63;
    const int quad = lane >> 4, l16 = lane & 15;

    const size_t headoff = (size_t)((b * 12 + h) * 197) * 64;
    const unsigned short* Qg = qkv + headoff;
    const unsigned short* Kg = qkv + (size_t)QSZ + headoff;
    const unsigned short* Vg = qkv + (size_t)2 * QSZ + headoff;

    // stage K: 197 x 64 bf16
    for (int idx = t; idx < 197 * 8; idx += 256) {
        int row = idx >> 3, c8 = (idx & 7) * 8;
        *(uint4*)&Ks[row * 72 + c8] = *(const uint4*)(Kg + (size_t)row * 64 + c8);
    }
    // stage V transposed, zero-padded kt in [197,232)
    for (int idx = t; idx < 58 * 64; idx += 256) {
        int g = idx >> 6, dd = idx & 63;
        int kt = g * 4;
        ushort4 vv;
        vv.x = (kt + 0 < 197) ? Vg[(size_t)(kt + 0) * 64 + dd] : (unsigned short)0;
        vv.y = (kt + 1 < 197) ? Vg[(size_t)(kt + 1) * 64 + dd] : (unsigned short)0;
        vv.z = (kt + 2 < 197) ? Vg[(size_t)(kt + 2) * 64 + dd] : (unsigned short)0;
        vv.w = (kt + 3 < 197) ? Vg[(size_t)(kt + 3) * 64 + dd] : (unsigned short)0;
        *(ushort4*)&Vt[dd * 232 + kt] = vv;
    }
    __syncthreads();

    unsigned short* Pw = Ps + w * (16 * 136);

    // each wave handles q-tiles tile = w, w+4, w+8, w+12 (13 tiles of 16 rows)
    for (int tile = w; tile < 13; tile += 4) {
        int rq = tile * 16 + l16;
        int tokq = rq < 197 ? rq : 196;
        bf16x8 aq0 = *(const bf16x8*)(Qg + (size_t)tokq * 64 + quad * 8);
        bf16x8 aq1 = *(const bf16x8*)(Qg + (size_t)tokq * 64 + 32 + quad * 8);

        // scores: 13 chunks of 16 kt-cols
        f32x4 s[13];
#pragma unroll
        for (int c = 0; c < 13; ++c) {
            int krow = c * 16 + l16;
            if (c == 12 && krow > 196) krow = 196;   // clamp LDS read (masked below)
            bf16x8 kb0 = *(const bf16x8*)&Ks[krow * 72 + quad * 8];
            bf16x8 kb1 = *(const bf16x8*)&Ks[krow * 72 + 32 + quad * 8];
            f32x4 zz = (f32x4){0.f, 0.f, 0.f, 0.f};
            zz = __builtin_amdgcn_mfma_f32_16x16x32_bf16(aq0, kb0, zz, 0, 0, 0);
            zz = __builtin_amdgcn_mfma_f32_16x16x32_bf16(aq1, kb1, zz, 0, 0, 0);
            s[c] = zz;
        }
        if (l16 >= 5) { s[12][0] = -1e30f; s[12][1] = -1e30f; s[12][2] = -1e30f; s[12][3] = -1e30f; }

        // softmax over 208 cols (rows = quad*4+r, cols spread over l16)
        float mx[4], lsum[4];
#pragma unroll
        for (int r = 0; r < 4; ++r) {
            float m = s[0][r];
#pragma unroll
            for (int c = 1; c < 13; ++c) m = fmaxf(m, s[c][r]);
#pragma unroll
            for (int d = 1; d < 16; d <<= 1) m = fmaxf(m, __shfl_xor(m, d));
            mx[r] = m;
            lsum[r] = 0.f;
        }
#pragma unroll
        for (int c = 0; c < 13; ++c)
#pragma unroll
            for (int r = 0; r < 4; ++r) {
                float p = __expf(s[c][r] - mx[r]);
                s[c][r] = p;
                lsum[r] += p;
            }
#pragma unroll
        for (int r = 0; r < 4; ++r)
#pragma unroll
            for (int d = 1; d < 16; d <<= 1) lsum[r] += __shfl_xor(lsum[r], d);

        f32x4 o[4];
#pragma unroll
        for (int j = 0; j < 4; ++j) o[j] = (f32x4){0.f, 0.f, 0.f, 0.f};

        // PV pass 1: P cols 0..127
#pragma unroll
        for (int c = 0; c < 8; ++c)
#pragma unroll
            for (int r = 0; r < 4; ++r)
                Pw[(quad * 4 + r) * 136 + c * 16 + l16] = f2bf(s[c][r]);
#pragma unroll
        for (int kc = 0; kc < 4; ++kc) {
            int kof = kc * 32 + quad * 8;
            bf16x8 ap = *(const bf16x8*)&Pw[l16 * 136 + kof];
#pragma unroll
            for (int j = 0; j < 4; ++j) {
                bf16x8 bv = *(const bf16x8*)&Vt[(j * 16 + l16) * 232 + kof];
                o[j] = __builtin_amdgcn_mfma_f32_16x16x32_bf16(ap, bv, o[j], 0, 0, 0);
            }
        }
        // PV pass 2: P cols 128..207 -> buffer cols 0..79; zero 80..95
#pragma unroll
        for (int r = 0; r < 4; ++r)
            Pw[(quad * 4 + r) * 136 + 80 + l16] = 0;
#pragma unroll
        for (int c = 8; c < 13; ++c)
#pragma unroll
            for (int r = 0; r < 4; ++r)
                Pw[(quad * 4 + r) * 136 + (c - 8) * 16 + l16] = f2bf(s[c][r]);
#pragma unroll
        for (int kc = 0; kc < 3; ++kc) {
            int kof = kc * 32 + quad * 8;
            bf16x8 ap = *(const bf16x8*)&Pw[l16 * 136 + kof];
#pragma unroll
            for (int j = 0; j < 4; ++j) {
                bf16x8 bv = *(const bf16x8*)&Vt[(j * 16 + l16) * 232 + 128 + kof];
                o[j] = __builtin_amdgcn_mfma_f32_16x16x32_bf16(ap, bv, o[j], 0, 0, 0);
            }
        }

        // epilogue: divide by l, store fp32 [B, tok, 768]
        int tokbase = tile * 16 + quad * 4;
#pragma unroll
        for (int r = 0; r < 4; ++r) {
            int tr = tokbase + r;
            if (tr >= 197) continue;
            float inv = 1.f / lsum[r];
#pragma unroll
            for (int j = 0; j < 4; ++j)
                out[((size_t)(b * 197 + tr)) * 768 + h * 64 + j * 16 + l16] = o[j][r] * inv;
        }
    }
}

extern "C" void kernel_launch(void* const* d_in, const int* in_sizes, int n_in,
                              void* d_out, int out_size, void* d_ws, size_t ws_size,
                              hipStream_t stream) {
    const float* X    = (const float*)d_in[0];   // [64,197,768]
    const float* W    = (const float*)d_in[1];   // [768,2304]
    const float* bias = (const float*)d_in[2];   // [2304]
    unsigned short* ws = (unsigned short*)d_ws;  // q|k|v bf16 planes then Wt bf16
    float* out = (float*)d_out;                  // [64,197,768]

    // Xb (bf16 X, padded to 12672 rows) lives in d_out scratch space —
    // fully dead until attn_kernel overwrites d_out at the end.
    unsigned short* Xb = (unsigned short*)d_out;

    x2bf_kernel<<<4728, 256, 0, stream>>>(X, Xb);
    wtrans_kernel<<<dim3(72, 24), dim3(32, 8), 0, stream>>>(W, ws + WT_OFF);
    qkv_gemm_kernel<<<dim3(18, 99), 256, 0, stream>>>(Xb, ws + WT_OFF, bias, ws);
    attn_kernel<<<dim3(12, 64), 256, 0, stream>>>(ws, out);
}